// Round 8
// baseline (405.546 us; speedup 1.0000x reference)
//
#include <hip/hip_runtime.h>
#include <stdint.h>

typedef unsigned short u16;
typedef unsigned int u32;

#define S_LEN 4096
#define EMB 2048
#define NH 16
#define HD 128
#define HDTOT 2048
#define T_TILES 32
#define KANCH 8
#define SM_SCALE 0.088388347648318447f

typedef __bf16 bf16x8 __attribute__((ext_vector_type(8)));
typedef float f32x4 __attribute__((ext_vector_type(4)));

typedef const __attribute__((address_space(1))) u32 ga_u32;
typedef __attribute__((address_space(3))) u32 lds_u32;

__device__ __forceinline__ u16 f2bf(float f) {
  u32 b = __builtin_bit_cast(u32, f);
  b = (b + 0x7FFFu + ((b >> 16) & 1u)) >> 16;
  return (u16)b;
}
__device__ __forceinline__ float bf2f(u16 u) {
  return __builtin_bit_cast(float, ((u32)u) << 16);
}
__device__ __forceinline__ f32x4 mfma16(bf16x8 a, bf16x8 b, f32x4 c) {
  return __builtin_amdgcn_mfma_f32_16x16x32_bf16(a, b, c, 0, 0, 0);
}

// ------- fused prep: z<4 -> transpose+convert weight z; z==4 -> convert x ---
__global__ __launch_bounds__(256) void k_prep(
    const float* __restrict__ x, u16* __restrict__ xb,
    const float* __restrict__ w0, const float* __restrict__ w1,
    const float* __restrict__ w2, const float* __restrict__ w3,
    u16* __restrict__ o0, u16* __restrict__ o1,
    u16* __restrict__ o2, u16* __restrict__ o3) {
  const int z = blockIdx.z;
  const int tid = threadIdx.x;
  if (z == 4) {  // x: fp32 -> bf16, 1024 blocks x 8192 elems
    int b = blockIdx.y * 32 + blockIdx.x;
    int base = b * 8192 + tid * 4;
#pragma unroll
    for (int it = 0; it < 8; ++it) {
      int i = base + it * 1024;
      float4 v = *(const float4*)(x + i);
      ushort4 o;
      o.x = f2bf(v.x); o.y = f2bf(v.y); o.z = f2bf(v.z); o.w = f2bf(v.w);
      *(ushort4*)(xb + i) = o;
    }
    return;
  }
  const float* w; u16* o;
  if (z == 0)      { w = w0; o = o0; }
  else if (z == 1) { w = w1; o = o1; }
  else if (z == 2) { w = w2; o = o2; }
  else             { w = w3; o = o3; }
  __shared__ float tile[64][68];
  int n0 = blockIdx.x * 64, k0 = blockIdx.y * 64;
  int r = tid >> 4, cq = (tid & 15) << 2;
  for (int p = 0; p < 4; ++p) {
    float4 v = *(const float4*)(w + (size_t)(k0 + r + p * 16) * EMB + n0 + cq);
    tile[r + p * 16][cq + 0] = v.x;
    tile[r + p * 16][cq + 1] = v.y;
    tile[r + p * 16][cq + 2] = v.z;
    tile[r + p * 16][cq + 3] = v.w;
  }
  __syncthreads();
  for (int p = 0; p < 4; ++p) {
    int rn = r + p * 16;
    ushort4 u;
    u.x = f2bf(tile[cq + 0][rn]);
    u.y = f2bf(tile[cq + 1][rn]);
    u.z = f2bf(tile[cq + 2][rn]);
    u.w = f2bf(tile[cq + 3][rn]);
    *(ushort4*)(o + (size_t)(n0 + rn) * EMB + k0 + cq) = u;
  }
}

// ------- v: [S][HDTOT] bf16 -> vT [HDTOT][S] bf16 -------
__global__ __launch_bounds__(256) void k_transpose_v(const u16* __restrict__ v,
                                                     u16* __restrict__ vt) {
  __shared__ u16 tile[64][72];
  int n0 = blockIdx.x * 64, s0 = blockIdx.y * 64;
  int tid = threadIdx.x;
  int r = tid >> 4, cq = (tid & 15) << 2;
  for (int p = 0; p < 4; ++p) {
    ushort4 u = *(const ushort4*)(v + (size_t)(s0 + r + p * 16) * HDTOT + n0 + cq);
    tile[r + p * 16][cq + 0] = u.x;
    tile[r + p * 16][cq + 1] = u.y;
    tile[r + p * 16][cq + 2] = u.z;
    tile[r + p * 16][cq + 3] = u.w;
  }
  __syncthreads();
  for (int p = 0; p < 4; ++p) {
    int rn = r + p * 16;
    ushort4 o;
    o.x = tile[cq + 0][rn];
    o.y = tile[cq + 1][rn];
    o.z = tile[cq + 2][rn];
    o.w = tile[cq + 3][rn];
    *(ushort4*)(vt + (size_t)(n0 + rn) * S_LEN + s0 + cq) = o;
  }
}

// ------- m97-style bf16 GEMM core, BANK-CONFLICT-FREE frag reads -----------
// LDS row = 32 bf16 (4 x 16B chunks). The 16B chunk stored at row position
// cpos holds GLOBAL chunk (cpos ^ (row&3) ^ ((row>>2)&3)) — a within-row
// permute folded into the global source address (coalescing unchanged; LDS
// dest stays the HW-required base+lane*16). Frag reads then hit 8 distinct
// banks per 16 lanes (2-way, free) instead of 2 banks (8-way, 2.94x).
__device__ __forceinline__ int swz(int row) { return (row & 3) ^ ((row >> 2) & 3); }

template <bool BF16OUT>
__device__ __forceinline__ void gemm_body(const u16* __restrict__ A,
                                          const u16* __restrict__ Bt,
                                          void* __restrict__ Cv,
                                          int N, int K, int m0, int n0,
                                          u16* As, u16* Bs) {
  const int tid = threadIdx.x;
  const int lane = tid & 63, wave = tid >> 6;
  const int quad = lane >> 4, l16 = lane & 15;
  const int wm = (wave >> 1) * 64, wn = (wave & 1) * 64;
  f32x4 acc[4][4] = {};

  const int flat0 = wave * 1024 + lane * 16;  // byte offset within 8KB tile
  for (int kt = 0; kt < K; kt += 32) {
    for (int half = 0; half < 2; ++half) {
      int flat = flat0 + half * 4096;
      int row = flat >> 6;
      int cpos = (flat >> 4) & 3;
      int colb = (cpos ^ swz(row)) << 4;  // global 16B-chunk byte offset
      const char* ga = (const char*)A + ((size_t)(m0 + row) * K + kt) * 2 + colb;
      const char* gb = (const char*)Bt + ((size_t)(n0 + row) * K + kt) * 2 + colb;
      int loff = wave * 1024 + half * 4096;  // wave-uniform LDS byte offset
      __builtin_amdgcn_global_load_lds((ga_u32*)ga, (lds_u32*)((char*)As + loff), 16, 0, 0);
      __builtin_amdgcn_global_load_lds((ga_u32*)gb, (lds_u32*)((char*)Bs + loff), 16, 0, 0);
    }
    __syncthreads();
    bf16x8 af[4], bfr[4];
    for (int mt = 0; mt < 4; ++mt) {
      int r = wm + mt * 16 + l16;
      af[mt] = *(const bf16x8*)(As + r * 32 + ((quad ^ swz(r)) << 3));
    }
    for (int nt = 0; nt < 4; ++nt) {
      int r = wn + nt * 16 + l16;
      bfr[nt] = *(const bf16x8*)(Bs + r * 32 + ((quad ^ swz(r)) << 3));
    }
    for (int mt = 0; mt < 4; ++mt)
      for (int nt = 0; nt < 4; ++nt)
        acc[mt][nt] = mfma16(af[mt], bfr[nt], acc[mt][nt]);
    __syncthreads();
  }
  for (int mt = 0; mt < 4; ++mt) {
    int row = m0 + wm + mt * 16 + quad * 4;
    for (int nt = 0; nt < 4; ++nt) {
      int col = n0 + wn + nt * 16 + l16;
      for (int r = 0; r < 4; ++r) {
        if (BF16OUT)
          ((u16*)Cv)[(size_t)(row + r) * N + col] = f2bf(acc[mt][nt][r]);
        else
          ((float*)Cv)[(size_t)(row + r) * N + col] = acc[mt][nt][r];
      }
    }
  }
}

template <bool BF16OUT>
__global__ __launch_bounds__(256) void k_gemm(const u16* __restrict__ A,
                                              const u16* __restrict__ Bt,
                                              void* __restrict__ Cv,
                                              int N, int K) {
  __shared__ __align__(16) u16 As[128 * 32];
  __shared__ __align__(16) u16 Bs[128 * 32];
  gemm_body<BF16OUT>(A, Bt, Cv, N, K, blockIdx.y * 128, blockIdx.x * 128, As, Bs);
}

// ------- fused QKV GEMM: one dispatch, B^T = [wqT;wkT;wvT] (contiguous) ----
__global__ __launch_bounds__(256) void k_gemm_qkv(const u16* __restrict__ A,
                                                  const u16* __restrict__ Bt,
                                                  u16* __restrict__ q,
                                                  u16* __restrict__ k,
                                                  u16* __restrict__ v) {
  __shared__ __align__(16) u16 As[128 * 32];
  __shared__ __align__(16) u16 Bs[128 * 32];
  const int nb = blockIdx.x;
  u16* out = (nb < 16) ? q : ((nb < 32) ? k : v);
  gemm_body<true>(A, Bt + (size_t)((nb >> 4) * 2048) * EMB, out,
                  HDTOT, EMB, blockIdx.y * 128, (nb & 15) * 128, As, Bs);
}

// ------- RoPE (half-split), vectorized 8-wide, in-place on q and k -------
__global__ __launch_bounds__(256) void k_rope(u16* __restrict__ q, u16* __restrict__ k,
                                              const float* __restrict__ ang) {
  int gid = blockIdx.x * 256 + threadIdx.x;  // S*NH*8 = 524288 threads
  int s = gid >> 7;
  int h = (gid >> 3) & (NH - 1);
  int dq = (gid & 7) << 3;
  const float* ap = ang + s * 64 + dq;
  float4 a0 = *(const float4*)(ap);
  float4 a1 = *(const float4*)(ap + 4);
  float sn[8], cs[8];
  __sincosf(a0.x, &sn[0], &cs[0]);
  __sincosf(a0.y, &sn[1], &cs[1]);
  __sincosf(a0.z, &sn[2], &cs[2]);
  __sincosf(a0.w, &sn[3], &cs[3]);
  __sincosf(a1.x, &sn[4], &cs[4]);
  __sincosf(a1.y, &sn[5], &cs[5]);
  __sincosf(a1.z, &sn[6], &cs[6]);
  __sincosf(a1.w, &sn[7], &cs[7]);
  size_t base = (size_t)s * HDTOT + h * HD + dq;
  u16* ptrs[2] = {q, k};
#pragma unroll
  for (int a = 0; a < 2; ++a) {
    u16* p = ptrs[a] + base;
    ushort4 x1a = *(const ushort4*)(p);
    ushort4 x1b = *(const ushort4*)(p + 4);
    ushort4 x2a = *(const ushort4*)(p + 64);
    ushort4 x2b = *(const ushort4*)(p + 68);
    u16 v1[8] = {x1a.x, x1a.y, x1a.z, x1a.w, x1b.x, x1b.y, x1b.z, x1b.w};
    u16 v2[8] = {x2a.x, x2a.y, x2a.z, x2a.w, x2b.x, x2b.y, x2b.z, x2b.w};
    u16 o1[8], o2[8];
#pragma unroll
    for (int e = 0; e < 8; ++e) {
      float f1 = bf2f(v1[e]), f2 = bf2f(v2[e]);
      o1[e] = f2bf(f1 * cs[e] - f2 * sn[e]);
      o2[e] = f2bf(f2 * cs[e] + f1 * sn[e]);
    }
    *(ushort4*)(p)      = make_ushort4(o1[0], o1[1], o1[2], o1[3]);
    *(ushort4*)(p + 4)  = make_ushort4(o1[4], o1[5], o1[6], o1[7]);
    *(ushort4*)(p + 64) = make_ushort4(o2[0], o2[1], o2[2], o2[3]);
    *(ushort4*)(p + 68) = make_ushort4(o2[4], o2[5], o2[6], o2[7]);
  }
}

// ------- swizzled LDS fragment reads (attention tiles) -------
__device__ __forceinline__ bf16x8 ldsfrag(const u16* __restrict__ sbuf, int r, int cb) {
  return *(const bf16x8*)(sbuf + r * 128 + (((cb ^ (r & 15)) << 3)));
}
__device__ __forceinline__ bf16x8 ldsfragV(const u16* __restrict__ sbuf, int r, int cb) {
  return *(const bf16x8*)(sbuf + r * 64 + (((cb ^ (r & 7)) << 3)));
}

// ------- block-sparse flash attention: one block per (t, h) ----------------
// R7 structure + anchor DEDUPE with multiplicity: duplicated tiles (and the
// diagonal when it's also an anchor) contribute m identical softmax columns
// == one column with exp scaled by m. Exact; saves ~13% of iterations.
__global__ __launch_bounds__(512, 4) void k_attn(const u16* __restrict__ q,
                                                 const u16* __restrict__ k,
                                                 const u16* __restrict__ vt,
                                                 const int* __restrict__ anch,
                                                 u16* __restrict__ out) {
  __shared__ __align__(16) u16 bufK[2][64 * 128];  // keys x dims (Q overlay at start)
  __shared__ __align__(16) u16 bufV[2][128 * 64];  // dims x keys
  __shared__ int s_tj[KANCH + 1];
  __shared__ float s_mult[KANCH + 1];
  __shared__ int s_nv;
  const int t = T_TILES - 1 - blockIdx.x;  // heavy (high-t) blocks first
  const int h = blockIdx.y;
  const int tid = threadIdx.x;
  const int lane = tid & 63, wave = tid >> 6;
  const int quad = lane >> 4, l16 = lane & 15;
  const int wq0 = wave * 16;

  int offK[2], offV[2];
#pragma unroll
  for (int p = 0; p < 2; ++p) {
    int krow = (wave * 2 + p) * 4 + (lane >> 4);
    int kcol = ((lane & 15) ^ (krow & 15)) << 3;
    offK[p] = (krow * HDTOT + kcol) * 2;
    int vrow = (wave * 2 + p) * 8 + (lane >> 3);
    int vcol = ((lane & 7) ^ (vrow & 7)) << 3;
    offV[p] = (vrow * S_LEN + vcol) * 2;
  }

  if (tid == 0) {
    int tl[KANCH + 1], ml[KANCH + 1];
    int nv = 0;
    for (int j = 0; j < KANCH; ++j) {
      int tj = anch[((h * T_TILES) + t) * KANCH + j];
      if (tj > t) continue;  // fully future-masked, skip
      bool found = false;
      for (int u = 0; u < nv; ++u)
        if (tl[u] == tj) { ml[u]++; found = true; break; }
      if (!found) { tl[nv] = tj; ml[nv] = 1; nv++; }
    }
    {  // local/diagonal tile (merge if already an anchor)
      bool found = false;
      for (int u = 0; u < nv; ++u)
        if (tl[u] == t) { ml[u]++; found = true; break; }
      if (!found) { tl[nv] = t; ml[nv] = 1; nv++; }
    }
    for (int u = 0; u < nv; ++u) { s_tj[u] = tl[u]; s_mult[u] = (float)ml[u]; }
    s_nv = nv;
  }

  // stage full Q tile (128x128) into bufK[0]+bufK[1] (contiguous 32KB)
  {
    const char* gq = (const char*)(q + (size_t)(t * 128) * HDTOT + h * HD);
    char* lq = (char*)bufK + wave * 4096;
#pragma unroll
    for (int p = 0; p < 4; ++p) {
      int qrow = (wave * 4 + p) * 4 + (lane >> 4);
      int qcol = ((lane & 15) ^ (qrow & 15)) << 3;
      __builtin_amdgcn_global_load_lds((ga_u32*)(gq + (qrow * HDTOT + qcol) * 2),
                                       (lds_u32*)(lq + p * 1024), 16, 0, 0);
    }
  }
  __syncthreads();  // Q arrived; s_tj/s_mult visible

  bf16x8 qf[4];
#pragma unroll
  for (int ks = 0; ks < 4; ++ks)
    qf[ks] = ldsfrag(&bufK[0][0], wq0 + l16, ks * 4 + quad);

  const int nv2 = 2 * s_nv;
  const char* kh = (const char*)(k + h * HD);
  const char* vh = (const char*)(vt + (size_t)(h * HD) * S_LEN);

  __syncthreads();  // all waves done reading Q before K0 DMA overwrites bufK[0]

  {
    int key0 = s_tj[0] * 128;
    const char* gk = kh + (size_t)key0 * (HDTOT * 2);
    const char* gv = vh + (size_t)key0 * 2;
    char* lk = (char*)bufK[0] + wave * 2048;
    char* lv = (char*)bufV[0] + wave * 2048;
#pragma unroll
    for (int p = 0; p < 2; ++p) {
      __builtin_amdgcn_global_load_lds((ga_u32*)(gk + offK[p]),
                                       (lds_u32*)(lk + p * 1024), 16, 0, 0);
      __builtin_amdgcn_global_load_lds((ga_u32*)(gv + offV[p]),
                                       (lds_u32*)(lv + p * 1024), 16, 0, 0);
    }
  }

  f32x4 oacc[8] = {};
  float m_st = -1e30f, l_st = 0.f;

  for (int i = 0; i < nv2; ++i) {
    const int par = i & 1;
    const u16* K_c = bufK[par];
    const u16* V_c = bufV[par];
    const int tj = s_tj[i >> 1];
    const float fm = s_mult[i >> 1];
    const int half = i & 1;
    const bool diag = (tj == t);

    __syncthreads();  // drains half-tile-i loads; WAR-protects buffer 1-par

    if (i + 1 < nv2) {
      int inx = i + 1;
      int key0 = s_tj[inx >> 1] * 128 + (inx & 1) * 64;
      const char* gk = kh + (size_t)key0 * (HDTOT * 2);
      const char* gv = vh + (size_t)key0 * 2;
      char* lk = (char*)bufK[1 - par] + wave * 2048;
      char* lv = (char*)bufV[1 - par] + wave * 2048;
#pragma unroll
      for (int p = 0; p < 2; ++p) {
        __builtin_amdgcn_global_load_lds((ga_u32*)(gk + offK[p]),
                                         (lds_u32*)(lk + p * 1024), 16, 0, 0);
        __builtin_amdgcn_global_load_lds((ga_u32*)(gv + offV[p]),
                                         (lds_u32*)(lv + p * 1024), 16, 0, 0);
      }
    }

    // S^T = K·Q^T
    f32x4 sacc[4] = {};
#pragma unroll
    for (int ks = 0; ks < 4; ++ks)
#pragma unroll
      for (int a = 0; a < 4; ++a) {
        bf16x8 kf = ldsfrag(K_c, a * 16 + l16, ks * 4 + quad);
        sacc[a] = mfma16(kf, qf[ks], sacc[a]);
      }

    // online softmax with multiplicity fm
    u32 pl[4], ph[4];
    float alpha;
    {
      const int qr = wq0 + l16;
      const int kb = half * 64;
      float rmax = -1e30f;
#pragma unroll
      for (int a = 0; a < 4; ++a) {
        f32x4 s4 = sacc[a];
#pragma unroll
        for (int r = 0; r < 4; ++r) {
          float sv = s4[r] * SM_SCALE;
          if (diag && (kb + a * 16 + quad * 4 + r > qr)) sv = -1e30f;
          s4[r] = sv;
          rmax = fmaxf(rmax, sv);
        }
        sacc[a] = s4;
      }
      rmax = fmaxf(rmax, __shfl_xor(rmax, 16));
      rmax = fmaxf(rmax, __shfl_xor(rmax, 32));
      float mnew = fmaxf(m_st, rmax);
      alpha = __expf(m_st - mnew);
      m_st = mnew;
      float rsum = 0.f;
#pragma unroll
      for (int a = 0; a < 4; ++a) {
        f32x4 s4 = sacc[a];
        float p0 = fm * __expf(s4[0] - mnew);
        float p1 = fm * __expf(s4[1] - mnew);
        float p2 = fm * __expf(s4[2] - mnew);
        float p3 = fm * __expf(s4[3] - mnew);
        rsum += (p0 + p1) + (p2 + p3);
        pl[a] = __builtin_amdgcn_perm(__builtin_bit_cast(u32, p1) + 0x8000u,
                                      __builtin_bit_cast(u32, p0) + 0x8000u,
                                      0x07060302u);
        ph[a] = __builtin_amdgcn_perm(__builtin_bit_cast(u32, p3) + 0x8000u,
                                      __builtin_bit_cast(u32, p2) + 0x8000u,
                                      0x07060302u);
      }
      rsum += __shfl_xor(rsum, 16);
      rsum += __shfl_xor(rsum, 32);
      l_st = l_st * alpha + rsum;
    }

    // rescale O
    {
      f32x4 av;
#pragma unroll
      for (int r = 0; r < 4; ++r)
        av[r] = __shfl(alpha, (lane & 48) | (quad * 4 + r));
#pragma unroll
      for (int nt = 0; nt < 8; ++nt) {
        f32x4 o4 = oacc[nt];
        o4[0] *= av[0]; o4[1] *= av[1]; o4[2] *= av[2]; o4[3] *= av[3];
        oacc[nt] = o4;
      }
    }

    // O += P·V
    const int srcA = ((quad & 1) << 5) + l16;
    const int srcB = srcA + 16;
    const int hi = quad >> 1;
#pragma unroll
    for (int c = 0; c < 2; ++c) {
      u32 x0 = __shfl(pl[2 * c], srcA), x1 = __shfl(ph[2 * c], srcA);
      u32 x2 = __shfl(pl[2 * c], srcB), x3 = __shfl(ph[2 * c], srcB);
      u32 y0 = __shfl(pl[2 * c + 1], srcA), y1 = __shfl(ph[2 * c + 1], srcA);
      u32 y2 = __shfl(pl[2 * c + 1], srcB), y3 = __shfl(ph[2 * c + 1], srcB);
      uint4 w;
      w.x = hi ? y0 : x0;
      w.y = hi ? y1 : x1;
      w.z = hi ? y2 : x2;
      w.w = hi ? y3 : x3;
      bf16x8 pa = __builtin_bit_cast(bf16x8, w);
#pragma unroll
      for (int nt = 0; nt < 8; ++nt) {
        bf16x8 vf = ldsfragV(V_c, nt * 16 + l16, c * 4 + quad);
        oacc[nt] = mfma16(pa, vf, oacc[nt]);
      }
    }
  }

  // epilogue
  {
    float linv = 1.0f / l_st;
    f32x4 iv;
#pragma unroll
    for (int r = 0; r < 4; ++r)
      iv[r] = __shfl(linv, (lane & 48) | (quad * 4 + r));
#pragma unroll
    for (int r = 0; r < 4; ++r) {
      size_t srow_o = (size_t)(t * 128 + wq0 + quad * 4 + r);
#pragma unroll
      for (int nt = 0; nt < 8; ++nt)
        out[srow_o * HDTOT + h * HD + nt * 16 + l16] = f2bf(oacc[nt][r] * iv[r]);
    }
  }
}

extern "C" void kernel_launch(void* const* d_in, const int* in_sizes, int n_in,
                              void* d_out, int out_size, void* d_ws, size_t ws_size,
                              hipStream_t stream) {
  const float* x   = (const float*)d_in[0];
  const float* wq  = (const float*)d_in[1];
  const float* wk  = (const float*)d_in[2];
  const float* wv  = (const float*)d_in[3];
  const float* wo  = (const float*)d_in[4];
  const float* ang = (const float*)d_in[5];
  const int* anch  = (const int*)d_in[6];

  char* ws = (char*)d_ws;
  const size_t SZ_SE = (size_t)S_LEN * HDTOT * sizeof(u16);  // 16 MB
  const size_t SZ_W  = (size_t)EMB * EMB * sizeof(u16);      // 8 MB
  u16* xb   = (u16*)(ws);
  u16* qb   = (u16*)(ws + SZ_SE);
  u16* kb   = (u16*)(ws + 2 * SZ_SE);
  u16* vb   = (u16*)(ws + 3 * SZ_SE);
  u16* vtb  = (u16*)(ws + 4 * SZ_SE);
  u16* attn = (u16*)(ws + 5 * SZ_SE);
  u16* wqT  = (u16*)(ws + 6 * SZ_SE);            // wqT,wkT,wvT contiguous ->
  u16* wkT  = (u16*)(ws + 6 * SZ_SE + SZ_W);     // single B^T for fused QKV
  u16* wvT  = (u16*)(ws + 6 * SZ_SE + 2 * SZ_W);
  u16* woT  = (u16*)(ws + 6 * SZ_SE + 3 * SZ_W);

  k_prep<<<dim3(32, 32, 5), 256, 0, stream>>>(x, xb, wq, wk, wv, wo, wqT, wkT, wvT, woT);
  k_gemm_qkv<<<dim3(48, 32), 256, 0, stream>>>(xb, wqT, qb, kb, vb);
  k_rope<<<2048, 256, 0, stream>>>(qb, kb, ang);
  k_transpose_v<<<dim3(32, 64), 256, 0, stream>>>(vb, vtb);
  k_attn<<<dim3(T_TILES, NH), 512, 0, stream>>>(qb, kb, vtb, anch, attn);
  k_gemm<false><<<dim3(16, 32), 256, 0, stream>>>(attn, woT, d_out, EMB, HDTOT);
}